// Round 2
// baseline (83.748 us; speedup 1.0000x reference)
//
#include <hip/hip_runtime.h>
#include <hip/hip_bf16.h>
#include <stdint.h>

// Shapes fixed by the reference: N=8192, F_IN=128, F_OUT=64.
// DTYPE (settled): f32 in/out, bf16 MFMA internal.
// Harness fixed floor ~78.8 us (256 MB ws re-poison is timed; untouchable).
// Round 14 = round-13 resubmit (container failed twice; no measurement).
// Round 13 = round-12 (83.46 us) + k2 LDS-read amortization:
//   k2 was LDS-read-bound, not MFMA-bound: 8 ds_read_b128 per j-step per wave
//   (4 B-frags + 4 E-vecs) x 4096 waves x 32 steps ~= 1.07 GB LDS traffic
//   ~= 7.8-10.3 us at 85-112 B/cy/CU, vs a 5.2 us MFMA floor.
//   Fix: 2 row-groups per wave (waves = 4 row-slots x 2 j-halves). Each
//   B0..B3 / E read now feeds 8 PV MFMAs + 2 ones-MFMAs -> B+E LDS traffic
//   halves. MFMA & VALU totals unchanged. j-halves combined through the
//   retired BtF buffer at the end (one extra barrier, ~0.1 us).
// Hard lessons: no per-block __threadfence (R9 L2 storm); LDS staging beats
// direct-L2 B-frag loads (R8); cross-block combine stays its own dispatch;
// exp() eliminated from k2 hot loop via g1/g2 x E1/E2 factorization (R12).
typedef float f32x4 __attribute__((ext_vector_type(4)));
typedef short s16x8 __attribute__((ext_vector_type(8)));
typedef short s16x4 __attribute__((ext_vector_type(4)));
typedef unsigned int u32x4 __attribute__((ext_vector_type(4)));

#define L2E 1.44269504088896f  // log2(e)

__device__ __forceinline__ float bf2f(unsigned short u) {
    return __uint_as_float(((unsigned int)u) << 16);
}
__device__ __forceinline__ unsigned short f2bf_rne(float f) {
    unsigned int u = __float_as_uint(f);
    u += 0x7fffu + ((u >> 16) & 1u);
    return (unsigned short)(u >> 16);
}

// ---------------------------------------------------------------------------
// k1: Wh = h@W (bf16 MFMA); per row i: g1=e^{f1}, g2=e^{.01 f1};
//     per col j (same index space): E1=e^{f2}, E2=e^{.01 f2};
//     whB = Wh^T in B-fragment-major layout:
//     whB[((jg*4 + b)*64 + lane)*8 + jj] = Wh[j = jg*32 + (lane>>4)*8 + jj]
//                                            [n = b*16 + (lane&15)]
// Grid: 128 x 256; block = 64 rows.
// ---------------------------------------------------------------------------
__global__ __launch_bounds__(256) void k1_wh(
    const float* __restrict__ hf,
    const float* __restrict__ Wf,
    const float* __restrict__ af,
    unsigned short* __restrict__ whB,
    float* __restrict__ g1L,
    float* __restrict__ g2L,
    float* __restrict__ E1L,
    float* __restrict__ E2L)
{
    __shared__ __align__(16) unsigned short Wt[64][136];  // [n][k] bf16, pad
    __shared__ __align__(16) unsigned short tb[64][72];   // [n][i_local]
    const int tid  = threadIdx.x;
    const int lane = tid & 63;
    const int w    = tid >> 6;
    const int col  = lane & 15;
    const int quad = lane >> 4;
    const int i0   = blockIdx.x * 64;

    // stage W (128x64 f32 row-major) -> Wt[n][k] bf16 (transposed)
    #pragma unroll
    for (int it = 0; it < 8; ++it) {
        int fidx = tid + it * 256;        // f32x4 index 0..2047
        int k  = fidx >> 4;               // 0..127
        int n4 = (fidx & 15) << 2;        // 0..60
        f32x4 wv = *(const f32x4*)&Wf[k * 64 + n4];
        #pragma unroll
        for (int e = 0; e < 4; ++e)
            Wt[n4 + e][k] = f2bf_rne(wv[e]);
    }
    __syncthreads();

    f32x4 D[4];
    #pragma unroll
    for (int f = 0; f < 4; ++f) D[f] = (f32x4){0.f, 0.f, 0.f, 0.f};

    const int rowA = i0 + w * 16 + col;  // A operand: m = lane&15
    #pragma unroll
    for (int cs = 0; cs < 4; ++cs) {     // K = 128 in 4 steps of 32
        f32x4 h0 = *(const f32x4*)&hf[(size_t)rowA * 128 + cs * 32 + quad * 8];
        f32x4 h1 = *(const f32x4*)&hf[(size_t)rowA * 128 + cs * 32 + quad * 8 + 4];
        s16x8 A;
        #pragma unroll
        for (int jj = 0; jj < 4; ++jj) {
            A[jj]     = (short)f2bf_rne(h0[jj]);
            A[4 + jj] = (short)f2bf_rne(h1[jj]);
        }
        #pragma unroll
        for (int f = 0; f < 4; ++f) {    // B[k][n]: n = f*16+col, k = cs*32+quad*8+jj
            s16x8 B = *(const s16x8*)&Wt[f * 16 + col][cs * 32 + quad * 8];
            D[f] = __builtin_amdgcn_mfma_f32_16x16x32_bf16(A, B, D[f], 0, 0, 0);
        }
    }

    float a1v[4], a2v[4];
    #pragma unroll
    for (int f = 0; f < 4; ++f) {
        a1v[f] = af[f * 16 + col];
        a2v[f] = af[64 + f * 16 + col];
    }

    // D layout: row = quad*4 + r, col-of-Wh = f*16 + (lane&15)
    #pragma unroll
    for (int r = 0; r < 4; ++r) {
        float s1 = D[0][r]*a1v[0] + D[1][r]*a1v[1] + D[2][r]*a1v[2] + D[3][r]*a1v[3];
        float s2 = D[0][r]*a2v[0] + D[1][r]*a2v[1] + D[2][r]*a2v[2] + D[3][r]*a2v[3];
        #pragma unroll
        for (int d = 1; d < 16; d <<= 1) {  // reduce over the 16 cols
            s1 += __shfl_xor(s1, d, 64);
            s2 += __shfl_xor(s2, d, 64);
        }
        if (col == 0) {
            int i = i0 + w * 16 + quad * 4 + r;
            g1L[i] = __builtin_amdgcn_exp2f(s1 * L2E);
            g2L[i] = __builtin_amdgcn_exp2f(s1 * (0.01f * L2E));
            E1L[i] = __builtin_amdgcn_exp2f(s2 * L2E);
            E2L[i] = __builtin_amdgcn_exp2f(s2 * (0.01f * L2E));
        }
        #pragma unroll
        for (int f = 0; f < 4; ++f)
            tb[f * 16 + col][w * 16 + quad * 4 + r] = f2bf_rne(D[f][r]);
    }
    __syncthreads();

    // emit whB: 512 chunks of 16 B (2 jg groups x 4 b x 64 lanes)
    for (int idx = tid; idx < 512; idx += 256) {
        int lane_o = idx & 63;
        int bq     = (idx >> 6) & 3;
        int jg_l   = idx >> 8;                       // 0..1
        int col_o  = lane_o & 15, quad_o = lane_o >> 4;
        u32x4 v = *(const u32x4*)&tb[bq * 16 + col_o][jg_l * 32 + quad_o * 8];
        size_t off = (((size_t)((i0 >> 5) + jg_l) * 4 + bq) * 64 + lane_o) * 8;
        *(u32x4*)&whB[off] = v;
    }
}

// ---------------------------------------------------------------------------
// k2: fused attention partials: 128 rows x one 1024-j chunk per block.
// Waves = 4 row-slots x 2 j-halves; each wave owns TWO 16-row groups
// (rg and rg+4) so every B0..B3 / E ds_read feeds 8 PV MFMAs + 2 ones-MFMAs
// (halves the LDS read traffic that bounded round 12).
// p = max(g1*E1_j, g2*E2_j) — no transcendentals in the hot loop.
// j-halves combined through the retired BtF buffer before the store.
// Grid: (64 row-tiles, 8 j-chunks) x 512 thr. 2 blocks/CU (16 waves).
// ---------------------------------------------------------------------------
__global__ __launch_bounds__(512, 4) void k2_attn(
    const unsigned short* __restrict__ whB,
    const float* __restrict__ g1L,
    const float* __restrict__ g2L,
    const float* __restrict__ E1L,
    const float* __restrict__ E2L,
    unsigned short* __restrict__ Apart,
    float* __restrict__ rsumP)
{
    __shared__ __align__(16) unsigned short BtF[16384];  // 8 jg x 2048, 32 KB
    __shared__ __align__(16) float E1s[256];
    __shared__ __align__(16) float E2s[256];
    const int tid  = threadIdx.x;
    const int lane = tid & 63;
    const int w    = tid >> 6;       // wave 0..7
    const int rg   = w & 3;          // row-slot 0..3
    const int jh   = w >> 2;         // j-half 0..1
    const int col  = lane & 15;
    const int quad = lane >> 4;
    const int i0   = blockIdx.x * 128;
    const int jb   = blockIdx.y * 1024;

    // A-fragment rows m = lane&15 for the two groups this wave owns
    const float g1a = g1L[i0 + rg * 16 + col];
    const float g2a = g2L[i0 + rg * 16 + col];
    const float g1b = g1L[i0 + (rg + 4) * 16 + col];
    const float g2b = g2L[i0 + (rg + 4) * 16 + col];

    f32x4 Da0 = (f32x4){0.f,0.f,0.f,0.f}, Da1 = Da0, Da2 = Da0, Da3 = Da0, Dsa = Da0;
    f32x4 Db0 = Da0, Db1 = Da0, Db2 = Da0, Db3 = Da0, Dsb = Da0;
    s16x8 ones;
    #pragma unroll
    for (int jj = 0; jj < 8; ++jj) ones[jj] = (short)0x3f80;  // bf16(1.0)

    for (int s = 0; s < 4; ++s) {            // 4 stages x 256 j
        __syncthreads();
        if (tid < 64)
            *(f32x4*)&E1s[tid * 4] = *(const f32x4*)&E1L[jb + (s << 8) + tid * 4];
        else if (tid < 128) {
            int t = tid - 64;
            *(f32x4*)&E2s[t * 4] = *(const f32x4*)&E2L[jb + (s << 8) + t * 4];
        }
        {   // contiguous 32 KB fragment-major copy: whB chunk -> BtF
            const unsigned short* src = whB + ((size_t)(jb >> 5) + s * 8) * 2048;
            #pragma unroll
            for (int it = 0; it < 4; ++it) {
                int idx = (tid + it * 512) * 8;      // u32x4 units * 8 ushorts
                *(u32x4*)&BtF[idx] = *(const u32x4*)&src[idx];
            }
        }
        __syncthreads();
        #pragma unroll
        for (int t = 0; t < 4; ++t) {        // this wave's 4 of the 8 j-steps
            const int j0 = jh * 32 + t * 64;
            const int jq = j0 + quad * 8;
            f32x4 ea1 = *(const f32x4*)&E1s[jq];
            f32x4 eb1 = *(const f32x4*)&E1s[jq + 4];
            f32x4 ea2 = *(const f32x4*)&E2s[jq];
            f32x4 eb2 = *(const f32x4*)&E2s[jq + 4];
            unsigned int pa[8], pb[8];
            #pragma unroll
            for (int e = 0; e < 4; ++e) {
                pa[e]     = __float_as_uint(fmaxf(g1a * ea1[e], g2a * ea2[e]));
                pa[4 + e] = __float_as_uint(fmaxf(g1a * eb1[e], g2a * eb2[e]));
                pb[e]     = __float_as_uint(fmaxf(g1b * ea1[e], g2b * ea2[e]));
                pb[4 + e] = __float_as_uint(fmaxf(g1b * eb1[e], g2b * eb2[e]));
            }
            union { u32x4 u4; s16x8 s8; } Aa, Ab;    // pack truncated bf16 pairs
            Aa.u4[0] = __builtin_amdgcn_perm(pa[1], pa[0], 0x07060302u);
            Aa.u4[1] = __builtin_amdgcn_perm(pa[3], pa[2], 0x07060302u);
            Aa.u4[2] = __builtin_amdgcn_perm(pa[5], pa[4], 0x07060302u);
            Aa.u4[3] = __builtin_amdgcn_perm(pa[7], pa[6], 0x07060302u);
            Ab.u4[0] = __builtin_amdgcn_perm(pb[1], pb[0], 0x07060302u);
            Ab.u4[1] = __builtin_amdgcn_perm(pb[3], pb[2], 0x07060302u);
            Ab.u4[2] = __builtin_amdgcn_perm(pb[5], pb[4], 0x07060302u);
            Ab.u4[3] = __builtin_amdgcn_perm(pb[7], pb[6], 0x07060302u);
            const unsigned short* bf = &BtF[(size_t)(j0 >> 5) * 2048 + lane * 8];
            s16x8 B0 = *(const s16x8*)(bf);
            s16x8 B1 = *(const s16x8*)(bf + 512);
            s16x8 B2 = *(const s16x8*)(bf + 1024);
            s16x8 B3 = *(const s16x8*)(bf + 1536);
            Da0 = __builtin_amdgcn_mfma_f32_16x16x32_bf16(Aa.s8, B0, Da0, 0, 0, 0);
            Da1 = __builtin_amdgcn_mfma_f32_16x16x32_bf16(Aa.s8, B1, Da1, 0, 0, 0);
            Da2 = __builtin_amdgcn_mfma_f32_16x16x32_bf16(Aa.s8, B2, Da2, 0, 0, 0);
            Da3 = __builtin_amdgcn_mfma_f32_16x16x32_bf16(Aa.s8, B3, Da3, 0, 0, 0);
            Dsa = __builtin_amdgcn_mfma_f32_16x16x32_bf16(Aa.s8, ones, Dsa, 0, 0, 0);
            Db0 = __builtin_amdgcn_mfma_f32_16x16x32_bf16(Ab.s8, B0, Db0, 0, 0, 0);
            Db1 = __builtin_amdgcn_mfma_f32_16x16x32_bf16(Ab.s8, B1, Db1, 0, 0, 0);
            Db2 = __builtin_amdgcn_mfma_f32_16x16x32_bf16(Ab.s8, B2, Db2, 0, 0, 0);
            Db3 = __builtin_amdgcn_mfma_f32_16x16x32_bf16(Ab.s8, B3, Db3, 0, 0, 0);
            Dsb = __builtin_amdgcn_mfma_f32_16x16x32_bf16(Ab.s8, ones, Dsb, 0, 0, 0);
        }
    }

    // combine the two j-halves through LDS (BtF & E1s are dead now).
    __syncthreads();
    float* Cf = (float*)BtF;   // 128 rows x 64 cols f32 = 32 KB, exact fit
    float* Sf = E1s;           // 128 row-sums
    if (jh == 1) {
        #pragma unroll
        for (int r = 0; r < 4; ++r) {
            int ra = (rg * 16 + quad * 4 + r) * 64;
            int rb = ((rg + 4) * 16 + quad * 4 + r) * 64;
            Cf[ra +      col] = Da0[r];
            Cf[ra + 16 + col] = Da1[r];
            Cf[ra + 32 + col] = Da2[r];
            Cf[ra + 48 + col] = Da3[r];
            Cf[rb +      col] = Db0[r];
            Cf[rb + 16 + col] = Db1[r];
            Cf[rb + 32 + col] = Db2[r];
            Cf[rb + 48 + col] = Db3[r];
            if (col == 0) {
                Sf[rg * 16 + quad * 4 + r]       = Dsa[r];
                Sf[(rg + 4) * 16 + quad * 4 + r] = Dsb[r];
            }
        }
    }
    __syncthreads();
    if (jh == 0) {
        unsigned short* Ap = Apart + (size_t)blockIdx.y * 524288;
        #pragma unroll
        for (int r = 0; r < 4; ++r) {
            int la = rg * 16 + quad * 4 + r;
            int lb = (rg + 4) * 16 + quad * 4 + r;
            int ia = i0 + la, ib = i0 + lb;
            Ap[(size_t)ia * 64 +      col] = f2bf_rne(Da0[r] + Cf[la * 64 +      col]);
            Ap[(size_t)ia * 64 + 16 + col] = f2bf_rne(Da1[r] + Cf[la * 64 + 16 + col]);
            Ap[(size_t)ia * 64 + 32 + col] = f2bf_rne(Da2[r] + Cf[la * 64 + 32 + col]);
            Ap[(size_t)ia * 64 + 48 + col] = f2bf_rne(Da3[r] + Cf[la * 64 + 48 + col]);
            Ap[(size_t)ib * 64 +      col] = f2bf_rne(Db0[r] + Cf[lb * 64 +      col]);
            Ap[(size_t)ib * 64 + 16 + col] = f2bf_rne(Db1[r] + Cf[lb * 64 + 16 + col]);
            Ap[(size_t)ib * 64 + 32 + col] = f2bf_rne(Db2[r] + Cf[lb * 64 + 32 + col]);
            Ap[(size_t)ib * 64 + 48 + col] = f2bf_rne(Db3[r] + Cf[lb * 64 + 48 + col]);
            if (col == 0) {
                rsumP[blockIdx.y * 8192 + ia] = Dsa[r] + Sf[la];
                rsumP[blockIdx.y * 8192 + ib] = Dsb[r] + Sf[lb];
            }
        }
    }
}

// ---------------------------------------------------------------------------
// k3: out(f32) = elu( sum_s bf2f(Apart[s]) / sum_s rsumP[s] ), x4 per thread.
// Kernel boundary = the cross-block fence (round-9 lesson). Grid: 512 x 256.
// ---------------------------------------------------------------------------
__global__ __launch_bounds__(256) void k3_combine(
    const unsigned short* __restrict__ Apart,
    const float* __restrict__ rsumP,
    float* __restrict__ out)
{
    int gid = blockIdx.x * 256 + threadIdx.x;  // 0 .. 131071
    int i  = gid >> 4;
    int c4 = (gid & 15) << 2;
    f32x4 num = (f32x4){0.f, 0.f, 0.f, 0.f};
    float den = 0.f;
    #pragma unroll
    for (int s = 0; s < 8; ++s) {
        s16x4 pv = *(const s16x4*)&Apart[(size_t)s * 524288 + (size_t)i * 64 + c4];
        #pragma unroll
        for (int e = 0; e < 4; ++e) num[e] += bf2f((unsigned short)pv[e]);
        den += rsumP[s * 8192 + i];
    }
    float rden = 1.f / den;
    f32x4 o;
    #pragma unroll
    for (int e = 0; e < 4; ++e) {
        float v = num[e] * rden;
        o[e] = v > 0.f ? v : (__builtin_amdgcn_exp2f(v * L2E) - 1.f);
    }
    *(f32x4*)&out[(size_t)i * 64 + c4] = o;
}

// ---------------------------------------------------------------------------
extern "C" void kernel_launch(void* const* d_in, const int* in_sizes, int n_in,
                              void* d_out, int out_size, void* d_ws, size_t ws_size,
                              hipStream_t stream) {
    const float* h = (const float*)d_in[0];  // 8192x128 f32
    const float* W = (const float*)d_in[1];  // 128x64 f32
    const float* a = (const float*)d_in[2];  // 128x1 f32
    float* out = (float*)d_out;              // 8192x64 f32

    char* ws = (char*)d_ws;
    unsigned short* whB   = (unsigned short*)ws;      // 1 MB fragment-major Wh^T
    float* g1L            = (float*)(ws + 1048576);   // 32 KB e^{f1}
    float* g2L            = (float*)(ws + 1081344);   // 32 KB e^{.01 f1}
    float* E1L            = (float*)(ws + 1114112);   // 32 KB e^{f2}
    float* E2L            = (float*)(ws + 1146880);   // 32 KB e^{.01 f2}
    unsigned short* Apart = (unsigned short*)(ws + 1179648);  // 8 x 8192x64 bf16 = 8 MB
    float* rsumP          = (float*)(ws + 9568256);   // 8 x 8192 f32 = 256 KB
    // total ws ~9.9 MB (ws_size ~256 MB per fill counters)

    k1_wh<<<128, 256, 0, stream>>>(h, W, a, whB, g1L, g2L, E1L, E2L);
    k2_attn<<<dim3(64, 8), 512, 0, stream>>>(whB, g1L, g2L, E1L, E2L, Apart, rsumP);
    k3_combine<<<512, 256, 0, stream>>>(Apart, rsumP, out);
}